// Round 4
// baseline (219.861 us; speedup 1.0000x reference)
//
#include <hip/hip_runtime.h>
#include <hip/hip_bf16.h>

// FourierFFTLayer: ifft(fft(x, axis=-1), axis=-1).real on real float32 input.
// Mathematically the identity; FFT round-trip rounding (~1e-5) is far below
// the 1.08e-1 absmax threshold -> pure copy at the HBM roofline.
//
// dur_us (~220 us) is dominated by harness reset traffic (~175 us of
// fillBufferAligned at 6.7 TB/s re-poisoning d_ws/d_out + restoring d_in).
// Our copy (268 MB -> ~43 us floor) is the only controllable slice.
// Nontemporal hints via native clang ext_vector_type (HIP float4 is a class
// and is rejected by __builtin_nontemporal_*).

typedef float v4f __attribute__((ext_vector_type(4)));

__global__ __launch_bounds__(256) void identity_copy_f4_nt(
        const v4f* __restrict__ in, v4f* __restrict__ out, int n4) {
    const int tid = blockIdx.x * blockDim.x + threadIdx.x;
    const int stride = gridDim.x * blockDim.x;
    // 8x unrolled grid-stride: 4096 blocks x 256 thr x 8 = 8388608 = n4 exactly.
    int i = tid;
    #pragma unroll 8
    for (int u = 0; u < 8; ++u) {
        if (i < n4) {
            v4f v = __builtin_nontemporal_load(&in[i]);
            __builtin_nontemporal_store(v, &out[i]);
        }
        i += stride;
    }
    // Tail safety for non-divisible sizes (not hit for n4 = 8388608).
    for (; i < n4; i += stride) {
        v4f v = __builtin_nontemporal_load(&in[i]);
        __builtin_nontemporal_store(v, &out[i]);
    }
}

extern "C" void kernel_launch(void* const* d_in, const int* in_sizes, int n_in,
                              void* d_out, int out_size, void* d_ws, size_t ws_size,
                              hipStream_t stream) {
    (void)in_sizes; (void)n_in; (void)d_ws; (void)ws_size;
    const v4f* x = (const v4f*)d_in[0];
    v4f* out = (v4f*)d_out;
    int n4 = out_size / 4;  // 33554432 / 4 = 8388608
    const int block = 256;
    const int grid = 4096;  // 16 blocks/CU; 8 float4 per thread
    identity_copy_f4_nt<<<grid, block, 0, stream>>>(x, out, n4);
}